// Round 4
// baseline (223.841 us; speedup 1.0000x reference)
//
#include <hip/hip_runtime.h>

#define NUM_INST 64
#define SLOT 12      // floats per slot: 9 used; 48B stride keeps 16B align, 8-bank spread
#define NSLOT 65     // 64 routing slots + 1 defensive zero slot
#define BLOCK 256
#define NWAVES 4
#define GRID 1792    // 7 blocks/CU -> 28 waves/CU; robust even if VGPR lands in (64,73]

typedef float f32x4 __attribute__((ext_vector_type(4)));
typedef float f32x2 __attribute__((ext_vector_type(2)));

__device__ __forceinline__ void pk_add(f32x2& acc, f32x2 v) {
    asm("v_pk_add_f32 %0, %0, %1" : "+v"(acc) : "v"(v));
}
__device__ __forceinline__ void pk_fma_sq(f32x2& acc, f32x2 v) {
    asm("v_pk_fma_f32 %0, %1, %1, %0" : "+v"(acc) : "v"(v));
}

__global__ __launch_bounds__(BLOCK) void vsl_main(const f32x4* __restrict__ rows,
                                                  const int* __restrict__ labels,
                                                  float* __restrict__ gacc, int n) {
    // per-wave private routing buffer: no cross-wave sharing -> no barriers in the loop
    __shared__ float lds[NWAVES][NSLOT * SLOT];
    const int tid = threadIdx.x;
    const int w = tid >> 6;
    const int lane = tid & 63;
    float* const wbase = &lds[w][0];

    // defensive zero slot (index 64): only reachable via the branchless clamp
    if (lane < 9) wbase[64 * SLOT + lane] = 0.0f;

    // lane d of each wave owns label d; accumulators as packed pairs
    f32x2 acc01 = {0, 0}, acc23 = {0, 0}, acc45 = {0, 0}, acc67 = {0, 0};
    float ssq = 0, cntf = 0;

    float* const pub = wbase + lane * SLOT;
    const int stride = GRID * BLOCK;

    // ---- prologue: load chunk 0 ----
    int i = blockIdx.x * BLOCK + tid;
    bool valid = (i < n);
    unsigned long long bv = __ballot(valid);
    int lbl = 0;
    f32x4 a = {0, 0, 0, 0}, b = {0, 0, 0, 0};
    if (valid) { lbl = labels[i]; a = rows[2 * i]; b = rows[2 * i + 1]; }

    while (bv) {
        // prefetch next chunk: its L2/HBM latency hides under routing+gather below
        const int inext = i + stride;
        const bool vnext = (inext < n);
        const unsigned long long bvn = __ballot(vnext);
        int lbln = 0;
        f32x4 an = {0, 0, 0, 0}, bn = {0, 0, 0, 0};
        if (vnext) { lbln = labels[inext]; an = rows[2 * inext]; bn = rows[2 * inext + 1]; }

        // packed ssq on the source lane (4 pk_fma instead of 8 scalar fma)
        f32x2 sq2 = {0, 0};
        pk_fma_sq(sq2, __builtin_shufflevector(a, a, 0, 1));
        pk_fma_sq(sq2, __builtin_shufflevector(a, a, 2, 3));
        pk_fma_sq(sq2, __builtin_shufflevector(b, b, 0, 1));
        pk_fma_sq(sq2, __builtin_shufflevector(b, b, 2, 3));
        const float sq = sq2.x + sq2.y;

        // publish to my private slot (same-wave DS is in-order)
        *(f32x4*)pub = a;
        *(f32x4*)(pub + 4) = b;
        pub[8] = sq;

        // 6 ballots on label bits -> mask of source lanes whose label == my lane id
        unsigned long long m = bv;
#pragma unroll
        for (int bpos = 0; bpos < 6; ++bpos) {
            const unsigned long long bb = __ballot((lbl >> bpos) & 1);
            m &= ((lane >> bpos) & 1) ? bb : ~bb;
        }
        cntf += (float)__popcll(m);  // exact integer counts, no atomic

        // keep the mask as two 32-bit halves: all per-step mask ops become 1-op, not 2
        unsigned mlo = (unsigned)m;
        unsigned mhi = (unsigned)(m >> 32);

        // writes visible before gathering (compiler barrier + drain)
        asm volatile("s_waitcnt lgkmcnt(0)" ::: "memory");

        // branchless gather: ffbl returns 0xFFFFFFFF on empty half, min-merge picks
        // the live half; clear logic is pure 32-bit (5 ops vs 8+ for 64-bit)
        while (mlo | mhi) {
            unsigned slo, shi;
            asm("v_ffbl_b32 %0, %1" : "=v"(slo) : "v"(mlo));
            asm("v_ffbl_b32 %0, %1" : "=v"(shi) : "v"(mhi));
            const unsigned s = min(slo, min(shi, 32u) + 32u);
            const bool uselo = (mlo != 0);
            const unsigned nlo = mlo & (mlo - 1);  // ==0 when mlo==0, so unconditional
            const unsigned nhi = mhi & (mhi - 1);
            mlo = nlo;
            mhi = uselo ? mhi : nhi;
            const float* sp = wbase + s * SLOT;
            const f32x4 p = *(const f32x4*)sp;
            const f32x4 q = *(const f32x4*)(sp + 4);
            const float r = sp[8];
            pk_add(acc01, __builtin_shufflevector(p, p, 0, 1));
            pk_add(acc23, __builtin_shufflevector(p, p, 2, 3));
            pk_add(acc45, __builtin_shufflevector(q, q, 0, 1));
            pk_add(acc67, __builtin_shufflevector(q, q, 2, 3));
            ssq += r;
        }

        // rotate prefetched chunk in
        i = inext; bv = bvn; lbl = lbln; a = an; b = bn;
    }

    // flush: reuse the routing buffer for per-wave totals (own region, own wave -> safe)
    float* fb = wbase + lane * SLOT;
    fb[0] = acc01.x; fb[1] = acc01.y; fb[2] = acc23.x; fb[3] = acc23.y;
    fb[4] = acc45.x; fb[5] = acc45.y; fb[6] = acc67.x; fb[7] = acc67.y;
    fb[8] = ssq; fb[9] = cntf;
    __syncthreads();

    // cross-wave reduce + one global atomic per (label, stat) per block
    for (int j = tid; j < NUM_INST * 10; j += BLOCK) {
        const int L = j / 10;
        const int st = j - L * 10;
        float v = 0;
#pragma unroll
        for (int ww = 0; ww < NWAVES; ++ww) v += lds[ww][L * SLOT + st];
        atomicAdd(&gacc[j], v);
    }
}

__global__ __launch_bounds__(64) void vsl_final(const float* __restrict__ gacc,
                                                float* __restrict__ out) {
    const int s = threadIdx.x;  // one thread per instance, 1 wave
    float val = 0.0f;
    const float* base = &gacc[s * 10];
    const float cnt = base[9];
    if (s != 0 && cnt > 0.0f) {
        const float ss = base[8];
        float m2 = 0.0f;
#pragma unroll
        for (int d = 0; d < 8; ++d) {
            const float sd = base[d];
            m2 += sd * sd;
        }
        val = (ss - m2 / cnt) / (cnt * 8.0f);
    }
#pragma unroll
    for (int off = 32; off > 0; off >>= 1) val += __shfl_down(val, off, 64);
    if (s == 0) out[0] = val;
}

extern "C" void kernel_launch(void* const* d_in, const int* in_sizes, int n_in,
                              void* d_out, int out_size, void* d_ws, size_t ws_size,
                              hipStream_t stream) {
    const float* variances = (const float*)d_in[0];  // [N, 8] fp32
    const int* labels = (const int*)d_in[1];         // [N] int32
    const int n = in_sizes[1];                       // N
    float* gacc = (float*)d_ws;                      // 640 floats of scratch

    hipMemsetAsync(d_ws, 0, NUM_INST * 10 * sizeof(float), stream);
    vsl_main<<<GRID, BLOCK, 0, stream>>>((const f32x4*)variances, labels, gacc, n);
    vsl_final<<<1, 64, 0, stream>>>(gacc, (float*)d_out);
}

// Round 5
// 206.259 us; speedup vs baseline: 1.0852x; 1.0852x over previous
//
#include <hip/hip_runtime.h>

#define NUM_INST 64
#define SLOT 12            // 48B stride: 16B-aligned, 8-bank-group spread
#define RCH 3              // rows per lane per phase
#define ZSLOT (RCH * 64)   // zero slot index (192)
#define NSLOT (ZSLOT + 1)  // 192 routing slots + 1 zero slot
#define BLOCK 256
#define NWAVES 4
#define GRID 1024          // 4 blocks/CU (LDS-limited: 37KB/block), 16 waves/CU

typedef float f32x4 __attribute__((ext_vector_type(4)));
typedef float f32x2 __attribute__((ext_vector_type(2)));

__device__ __forceinline__ void pk_add(f32x2& acc, f32x2 v) {
    asm("v_pk_add_f32 %0, %0, %1" : "+v"(acc) : "v"(v));
}
__device__ __forceinline__ void pk_fma_sq(f32x2& acc, f32x2 v) {
    asm("v_pk_fma_f32 %0, %1, %1, %0" : "+v"(acc) : "v"(v));
}

// extract next set bit across 3 merged 64-bit masks; ZSLOT when empty (per-lane selects)
__device__ __forceinline__ int take3(unsigned long long& m0, unsigned long long& m1,
                                     unsigned long long& m2) {
    const bool u0 = (m0 != 0), u1 = (m1 != 0);
    const unsigned long long sel = u0 ? m0 : (u1 ? m1 : m2);
    const int base = u0 ? 0 : (u1 ? 64 : 128);
    const int s = sel ? (base + (int)__builtin_ctzll(sel)) : ZSLOT;
    const unsigned long long cl = sel & (sel - 1);  // sel==0 -> cl==0, harmless
    m0 = u0 ? cl : m0;
    m1 = (!u0 && u1) ? cl : m1;
    m2 = (!u0 && !u1) ? cl : m2;
    return s;
}

__global__ __launch_bounds__(BLOCK, 4) void vsl_main(const f32x4* __restrict__ rows,
                                                     const int* __restrict__ labels,
                                                     float* __restrict__ gacc, int n) {
    // per-wave private routing buffer: no cross-wave sharing -> no barriers in the loop
    __shared__ float lds[NWAVES][NSLOT * SLOT];
    const int tid = threadIdx.x;
    const int w = tid >> 6;
    const int lane = tid & 63;
    float* const wbase = &lds[w][0];

    // zero slot: branchless gather tail reads this (broadcast, adds 0)
    if (lane < 8) wbase[ZSLOT * SLOT + lane] = 0.0f;

    // lane d of each wave owns label d
    f32x2 acc01 = {0, 0}, acc23 = {0, 0}, acc45 = {0, 0}, acc67 = {0, 0};
    f32x2 ssq2 = {0, 0};
    float cntf = 0;

    f32x4* const pub0 = (f32x4*)(wbase + lane * SLOT);
    f32x4* const pub1 = (f32x4*)(wbase + (64 + lane) * SLOT);
    f32x4* const pub2 = (f32x4*)(wbase + (128 + lane) * SLOT);

    const int S = GRID * BLOCK;
    const int phaseStride = RCH * S;
    const int nph = (n + phaseStride - 1) / phaseStride;  // uniform across all threads

    int i0 = blockIdx.x * BLOCK + tid;
    for (int ph = 0; ph < nph; ++ph, i0 += phaseStride) {
        const int i1 = i0 + S;
        const int i2 = i1 + S;
        const bool v0 = (i0 < n), v1 = (i1 < n), v2 = (i2 < n);

        // ---- issue all 9 VMEM back-to-back: 6.75KB/wave in flight ----
        int l0 = 0, l1 = 0, l2 = 0;
        f32x4 a0 = {0, 0, 0, 0}, b0 = {0, 0, 0, 0};
        f32x4 a1 = {0, 0, 0, 0}, b1 = {0, 0, 0, 0};
        f32x4 a2 = {0, 0, 0, 0}, b2 = {0, 0, 0, 0};
        if (v0) { l0 = labels[i0]; a0 = rows[2 * i0]; b0 = rows[2 * i0 + 1]; }
        if (v1) { l1 = labels[i1]; a1 = rows[2 * i1]; b1 = rows[2 * i1 + 1]; }
        if (v2) { l2 = labels[i2]; a2 = rows[2 * i2]; b2 = rows[2 * i2 + 1]; }

        // publish: 6x ds_write_b128 (ssq computed on gather side, like round-0)
        pub0[0] = a0; pub0[1] = b0;
        pub1[0] = a1; pub1[1] = b1;
        pub2[0] = a2; pub2[1] = b2;

        // 18 ballots -> per-owner masks for 3 chunks, amortized over 192 rows
        unsigned long long m0 = __ballot(v0), m1 = __ballot(v1), m2 = __ballot(v2);
#pragma unroll
        for (int bpos = 0; bpos < 6; ++bpos) {
            const unsigned long long t0 = __ballot((l0 >> bpos) & 1);
            const unsigned long long t1 = __ballot((l1 >> bpos) & 1);
            const unsigned long long t2 = __ballot((l2 >> bpos) & 1);
            const bool mybit = (lane >> bpos) & 1;
            m0 &= mybit ? t0 : ~t0;
            m1 &= mybit ? t1 : ~t1;
            m2 &= mybit ? t2 : ~t2;
        }
        cntf += (float)(__popcll(m0) + __popcll(m1) + __popcll(m2));

        // publish visible before gather (same-wave DS in-order; clobber stops reordering)
        asm volatile("s_waitcnt lgkmcnt(0)" ::: "memory");

        // ---- grouped gather: 4 slots per step -> 8 ds_read_b128 in flight,
        //      LDS latency paid once per group instead of once per row ----
        while (m0 | m1 | m2) {
            const int s0 = take3(m0, m1, m2);
            const int s1 = take3(m0, m1, m2);
            const int s2 = take3(m0, m1, m2);
            const int s3 = take3(m0, m1, m2);
            const f32x4* q0 = (const f32x4*)(wbase + s0 * SLOT);
            const f32x4* q1 = (const f32x4*)(wbase + s1 * SLOT);
            const f32x4* q2 = (const f32x4*)(wbase + s2 * SLOT);
            const f32x4* q3 = (const f32x4*)(wbase + s3 * SLOT);
            const f32x4 pa0 = q0[0], pb0 = q0[1];
            const f32x4 pa1 = q1[0], pb1 = q1[1];
            const f32x4 pa2 = q2[0], pb2 = q2[1];
            const f32x4 pa3 = q3[0], pb3 = q3[1];

            pk_add(acc01, __builtin_shufflevector(pa0, pa0, 0, 1));
            pk_add(acc23, __builtin_shufflevector(pa0, pa0, 2, 3));
            pk_add(acc45, __builtin_shufflevector(pb0, pb0, 0, 1));
            pk_add(acc67, __builtin_shufflevector(pb0, pb0, 2, 3));
            pk_fma_sq(ssq2, __builtin_shufflevector(pa0, pa0, 0, 1));
            pk_fma_sq(ssq2, __builtin_shufflevector(pa0, pa0, 2, 3));
            pk_fma_sq(ssq2, __builtin_shufflevector(pb0, pb0, 0, 1));
            pk_fma_sq(ssq2, __builtin_shufflevector(pb0, pb0, 2, 3));

            pk_add(acc01, __builtin_shufflevector(pa1, pa1, 0, 1));
            pk_add(acc23, __builtin_shufflevector(pa1, pa1, 2, 3));
            pk_add(acc45, __builtin_shufflevector(pb1, pb1, 0, 1));
            pk_add(acc67, __builtin_shufflevector(pb1, pb1, 2, 3));
            pk_fma_sq(ssq2, __builtin_shufflevector(pa1, pa1, 0, 1));
            pk_fma_sq(ssq2, __builtin_shufflevector(pa1, pa1, 2, 3));
            pk_fma_sq(ssq2, __builtin_shufflevector(pb1, pb1, 0, 1));
            pk_fma_sq(ssq2, __builtin_shufflevector(pb1, pb1, 2, 3));

            pk_add(acc01, __builtin_shufflevector(pa2, pa2, 0, 1));
            pk_add(acc23, __builtin_shufflevector(pa2, pa2, 2, 3));
            pk_add(acc45, __builtin_shufflevector(pb2, pb2, 0, 1));
            pk_add(acc67, __builtin_shufflevector(pb2, pb2, 2, 3));
            pk_fma_sq(ssq2, __builtin_shufflevector(pa2, pa2, 0, 1));
            pk_fma_sq(ssq2, __builtin_shufflevector(pa2, pa2, 2, 3));
            pk_fma_sq(ssq2, __builtin_shufflevector(pb2, pb2, 0, 1));
            pk_fma_sq(ssq2, __builtin_shufflevector(pb2, pb2, 2, 3));

            pk_add(acc01, __builtin_shufflevector(pa3, pa3, 0, 1));
            pk_add(acc23, __builtin_shufflevector(pa3, pa3, 2, 3));
            pk_add(acc45, __builtin_shufflevector(pb3, pb3, 0, 1));
            pk_add(acc67, __builtin_shufflevector(pb3, pb3, 2, 3));
            pk_fma_sq(ssq2, __builtin_shufflevector(pa3, pa3, 0, 1));
            pk_fma_sq(ssq2, __builtin_shufflevector(pa3, pa3, 2, 3));
            pk_fma_sq(ssq2, __builtin_shufflevector(pb3, pb3, 0, 1));
            pk_fma_sq(ssq2, __builtin_shufflevector(pb3, pb3, 2, 3));
        }
    }

    // flush: reuse routing buffer for per-wave totals (own region, own wave -> safe)
    float* fb = wbase + lane * SLOT;
    fb[0] = acc01.x; fb[1] = acc01.y; fb[2] = acc23.x; fb[3] = acc23.y;
    fb[4] = acc45.x; fb[5] = acc45.y; fb[6] = acc67.x; fb[7] = acc67.y;
    fb[8] = ssq2.x + ssq2.y; fb[9] = cntf;
    __syncthreads();

    // cross-wave reduce + one global atomic per (label, stat) per block
    for (int j = tid; j < NUM_INST * 10; j += BLOCK) {
        const int L = j / 10;
        const int st = j - L * 10;
        float v = 0;
#pragma unroll
        for (int ww = 0; ww < NWAVES; ++ww) v += lds[ww][L * SLOT + st];
        atomicAdd(&gacc[j], v);
    }
}

__global__ __launch_bounds__(64) void vsl_final(const float* __restrict__ gacc,
                                                float* __restrict__ out) {
    const int s = threadIdx.x;  // one thread per instance, 1 wave
    float val = 0.0f;
    const float* base = &gacc[s * 10];
    const float cnt = base[9];
    if (s != 0 && cnt > 0.0f) {
        const float ss = base[8];
        float m2 = 0.0f;
#pragma unroll
        for (int d = 0; d < 8; ++d) {
            const float sd = base[d];
            m2 += sd * sd;
        }
        val = (ss - m2 / cnt) / (cnt * 8.0f);
    }
#pragma unroll
    for (int off = 32; off > 0; off >>= 1) val += __shfl_down(val, off, 64);
    if (s == 0) out[0] = val;
}

extern "C" void kernel_launch(void* const* d_in, const int* in_sizes, int n_in,
                              void* d_out, int out_size, void* d_ws, size_t ws_size,
                              hipStream_t stream) {
    const float* variances = (const float*)d_in[0];  // [N, 8] fp32
    const int* labels = (const int*)d_in[1];         // [N] int32
    const int n = in_sizes[1];                       // N
    float* gacc = (float*)d_ws;                      // 640 floats of scratch

    hipMemsetAsync(d_ws, 0, NUM_INST * 10 * sizeof(float), stream);
    vsl_main<<<GRID, BLOCK, 0, stream>>>((const f32x4*)variances, labels, gacc, n);
    vsl_final<<<1, 64, 0, stream>>>(gacc, (float*)d_out);
}